// Round 12
// baseline (280.973 us; speedup 1.0000x reference)
//
#include <hip/hip_runtime.h>
#include <hip/hip_bf16.h>

// NodeNetwork: mi = segsum(ea*x[row] -> col), mo = segsum(ea*x[col] -> row)
// out = tanh(tanh([mi|mo|x] @ W1 + b1) @ W2 + b2)
// N=100000, D=32, O=64, E=1600000
//
// R12: accum micro-fixes guided by R11 counters (FETCH 153MB = pay read
// twice in sort phases; VALUBusy 25% = 4 loads in flight short of parity):
//  1. register-stash chunk records (rec[12]) -> count & place from regs,
//     one global pay pass instead of two.
//  2. gather quad chains unrolled x2 -> 8 independent x-loads in flight.
// R11 baseline: 257us total, accum 117us.

#define DFEAT 32
#define OFEAT 64
#define EPB   2048            // edges per partition block -> 4096 records
#define KEYS_PER_BIN 128      // partition bin = key >> 7 ; lkey = key & 127
#define MAXBIN 2048
#define CAP   3072            // records staged per chunk (24 KB)
#define NJ    (CAP / 256)     // 12 stash slots per thread

typedef unsigned long long u64;

__device__ __forceinline__ float rdlane(float v, int l) {
    return __int_as_float(__builtin_amdgcn_readlane(__float_as_int(v), l));
}

// ---- A. per-block histogram over bins ----
__global__ __launch_bounds__(256) void hist_part(
    const int* __restrict__ ei, int* __restrict__ blockhist, int E, int NBIN)
{
    __shared__ int lh[MAXBIN];
    int blk = blockIdx.x;
    for (int i = threadIdx.x; i < NBIN; i += 256) lh[i] = 0;
    __syncthreads();
    int e0 = blk * EPB;
    #pragma unroll
    for (int j = 0; j < 8; ++j) {
        int e = e0 + j * 256 + threadIdx.x;
        if (e < E) {
            int r = ei[e], c = ei[E + e];
            atomicAdd(&lh[(2 * c) >> 7], 1);
            atomicAdd(&lh[(2 * r + 1) >> 7], 1);
        }
    }
    __syncthreads();
    for (int i = threadIdx.x; i < NBIN; i += 256)
        blockhist[(long long)blk * NBIN + i] = lh[i];
}

// ---- B. column scan: per-bin prefix over blocks -> ofsT, bintotal ----
__global__ __launch_bounds__(64) void colscan(
    const int* __restrict__ blockhist, int* __restrict__ ofsT,
    int* __restrict__ bintotal, int nPB, int NBIN)
{
    int bin  = blockIdx.x;
    int lane = threadIdx.x;
    int run = 0;
    for (int b0 = 0; b0 < nPB; b0 += 64) {
        int b = b0 + lane;
        int v = (b < nPB) ? blockhist[(long long)b * NBIN + bin] : 0;
        int s = v;
        #pragma unroll
        for (int d = 1; d < 64; d <<= 1) {
            int t = __shfl_up(s, d, 64);
            if (lane >= d) s += t;
        }
        if (b < nPB) ofsT[(long long)bin * nPB + b] = s - v + run;
        run += __shfl(s, 63, 64);
    }
    if (lane == 0) bintotal[bin] = run;
}

// ---- C. exclusive scan of (even-padded) bin totals, up to 2048 bins ----
__global__ __launch_bounds__(1024) void scan_bins(
    const int* __restrict__ bintotal, int* __restrict__ binbase, int NBIN)
{
    __shared__ int s[1024];
    int t = threadIdx.x;
    int i0 = 2 * t, i1 = 2 * t + 1;
    int p0 = (i0 < NBIN) ? ((bintotal[i0] + 1) & ~1) : 0;  // even-pad -> 16B align
    int p1 = (i1 < NBIN) ? ((bintotal[i1] + 1) & ~1) : 0;
    int v = p0 + p1;
    s[t] = v;
    __syncthreads();
    for (int o = 1; o < 1024; o <<= 1) {
        int u = (t >= o) ? s[t - o] : 0;
        __syncthreads();
        s[t] += u;
        __syncthreads();
    }
    int excl = s[t] - v;
    if (i0 < NBIN) binbase[i0] = excl;
    if (i1 < NBIN) binbase[i1] = excl + p0;
}

// ---- D. partition: LDS reorder + coalesced flush (binof tag) ----
__global__ __launch_bounds__(256) void partition_kernel(
    const int* __restrict__ ei, const float* __restrict__ ea,
    const int* __restrict__ ofsT, const int* __restrict__ binbase,
    u64* __restrict__ pay, int E, int NBIN, int nPB)
{
    __shared__ int lofs[MAXBIN + 1];
    __shared__ int lcur[MAXBIN];
    __shared__ int lbase[MAXBIN];
    __shared__ u64 stag[2 * EPB];             // 32 KB
    __shared__ unsigned short binof[2 * EPB]; // 8 KB
    int blk = blockIdx.x, tid = threadIdx.x;
    int e0 = blk * EPB;

    for (int i = tid; i < NBIN; i += 256) lcur[i] = 0;
    __syncthreads();

    // pass 1: load edges (kept in regs), LDS histogram
    int r[8], c[8]; float a[8]; bool valid[8];
    #pragma unroll
    for (int j = 0; j < 8; ++j) {
        int e = e0 + j * 256 + tid;
        valid[j] = (e < E);
        if (valid[j]) {
            r[j] = ei[e]; c[j] = ei[E + e]; a[j] = ea[e];
            atomicAdd(&lcur[(2 * c[j]) >> 7], 1);
            atomicAdd(&lcur[(2 * r[j] + 1) >> 7], 1);
        }
    }
    __syncthreads();

    // wave 0: exclusive scan lcur -> lofs
    if (tid < 64) {
        int runc = 0;
        for (int b0 = 0; b0 < NBIN; b0 += 64) {
            int i = b0 + tid;
            int v = (i < NBIN) ? lcur[i] : 0;
            int s = v;
            #pragma unroll
            for (int d = 1; d < 64; d <<= 1) {
                int t2 = __shfl_up(s, d, 64);
                if (tid >= d) s += t2;
            }
            if (i < NBIN) lofs[i] = s - v + runc;
            runc += __shfl(s, 63, 64);
        }
        if (tid == 0) lofs[NBIN] = runc;
    }
    __syncthreads();

    // reset tickets, compute global bases for this block
    for (int i = tid; i < NBIN; i += 256) {
        lcur[i] = 0;
        lbase[i] = binbase[i] + ofsT[(long long)i * nPB + blk];
    }
    __syncthreads();

    // pass 2: place records into LDS staging (sorted by bin) + bin tag
    #pragma unroll
    for (int j = 0; j < 8; ++j) {
        if (valid[j]) {
            unsigned int ab = (unsigned int)__float_as_int(a[j]);
            {
                int key = 2 * c[j]; int bin = key >> 7;      // mi: src = r
                int t2 = atomicAdd(&lcur[bin], 1);
                int pos = lofs[bin] + t2;
                stag[pos] = ((u64)ab << 32) |
                    (unsigned int)(r[j] | ((key & 127) << 17));
                binof[pos] = (unsigned short)bin;
            }
            {
                int key = 2 * r[j] + 1; int bin = key >> 7;  // mo: src = c
                int t2 = atomicAdd(&lcur[bin], 1);
                int pos = lofs[bin] + t2;
                stag[pos] = ((u64)ab << 32) |
                    (unsigned int)(c[j] | ((key & 127) << 17));
                binof[pos] = (unsigned short)bin;
            }
        }
    }
    __syncthreads();

    // flush: contiguous runs per bin -> mostly full-line global writes
    int total = lofs[NBIN];
    for (int i = tid; i < total; i += 256) {
        int bn = binof[i];
        pay[lbase[bn] + (i - lofs[bn])] = stag[i];
    }
}

// ---- E. accum: reg-stash sort + quad-chain x2-unrolled register gather ----
__global__ __launch_bounds__(256) void accum_sortgather(
    const float* __restrict__ x,
    const int* __restrict__ binbase, const int* __restrict__ bintotal,
    const u64* __restrict__ pay,
    float* __restrict__ mi, float* __restrict__ mo, int NK)
{
    __shared__ u64 srec[CAP];                 // 24 KB, records sorted by key
    __shared__ int lcnt[KEYS_PER_BIN];
    __shared__ int lofs[KEYS_PER_BIN];
    __shared__ int lcur[KEYS_PER_BIN];

    int b = blockIdx.x, tid = threadIdx.x;
    int base = binbase[b];
    int n    = bintotal[b];
    int wid  = tid >> 6;        // 0..3: wave -> owns keys [wid*32, wid*32+32)
    int lane = tid & 63;
    int half = lane >> 5;       // records strided by 2 across halves
    int feat = lane & 31;

    float accA[8], accB[8], accC[8], accD[8];
    #pragma unroll
    for (int p = 0; p < 8; ++p) {
        accA[p] = 0.0f; accB[p] = 0.0f; accC[p] = 0.0f; accD[p] = 0.0f;
    }

    for (int c0 = 0; c0 < n; c0 += CAP) {
        int cn = min(n - c0, CAP);

        // stash this chunk's records in registers (single global pass)
        u64 rec[NJ];
        #pragma unroll
        for (int j = 0; j < NJ; ++j) {
            int i = tid + j * 256;
            if (i < cn) rec[j] = pay[base + c0 + i];
        }
        if (tid < KEYS_PER_BIN) lcnt[tid] = 0;
        __syncthreads();
        // count keys from registers
        #pragma unroll
        for (int j = 0; j < NJ; ++j) {
            int i = tid + j * 256;
            if (i < cn) atomicAdd(&lcnt[((int)rec[j] >> 17) & 127], 1);
        }
        __syncthreads();
        // exclusive scan of 128 counters (wave 0, 2 keys/lane)
        if (tid < 64) {
            int v0 = lcnt[2 * tid], v1 = lcnt[2 * tid + 1];
            int s = v0 + v1, ss = s;
            #pragma unroll
            for (int d = 1; d < 64; d <<= 1) {
                int t = __shfl_up(ss, d, 64);
                if (tid >= d) ss += t;
            }
            int excl = ss - s;
            lofs[2 * tid] = excl;      lofs[2 * tid + 1] = excl + v0;
            lcur[2 * tid] = excl;      lcur[2 * tid + 1] = excl + v0;
        }
        __syncthreads();
        // place records from registers, sorted by key
        #pragma unroll
        for (int j = 0; j < NJ; ++j) {
            int i = tid + j * 256;
            if (i < cn) {
                int t2 = atomicAdd(&lcur[((int)rec[j] >> 17) & 127], 1);
                srec[t2] = rec[j];
            }
        }
        __syncthreads();

        // gather: 8 quads of keys per wave; chains x2-unrolled -> 8 loads
        #pragma unroll
        for (int p = 0; p < 8; ++p) {
            int kb = wid * 32 + 4 * p;
            int s0 = lofs[kb + 0], e0 = s0 + lcnt[kb + 0];
            int s1 = lofs[kb + 1], e1 = s1 + lcnt[kb + 1];
            int s2 = lofs[kb + 2], e2 = s2 + lcnt[kb + 2];
            int s3 = lofs[kb + 3], e3 = s3 + lcnt[kb + 3];
            int i0 = s0 + half, i1 = s1 + half, i2 = s2 + half, i3 = s3 + half;
            float a0 = accA[p], a1 = accB[p], a2 = accC[p], a3 = accD[p];
            // deep loop: 2 records per chain per iteration (8 loads in flight)
            while (i0 + 2 < e0 && i1 + 2 < e1 && i2 + 2 < e2 && i3 + 2 < e3) {
                u64 r0a = srec[i0], r0b = srec[i0 + 2];
                u64 r1a = srec[i1], r1b = srec[i1 + 2];
                u64 r2a = srec[i2], r2b = srec[i2 + 2];
                u64 r3a = srec[i3], r3b = srec[i3 + 2];
                float x0a = x[(long long)((int)r0a & 0x1FFFF) * DFEAT + feat];
                float x0b = x[(long long)((int)r0b & 0x1FFFF) * DFEAT + feat];
                float x1a = x[(long long)((int)r1a & 0x1FFFF) * DFEAT + feat];
                float x1b = x[(long long)((int)r1b & 0x1FFFF) * DFEAT + feat];
                float x2a = x[(long long)((int)r2a & 0x1FFFF) * DFEAT + feat];
                float x2b = x[(long long)((int)r2b & 0x1FFFF) * DFEAT + feat];
                float x3a = x[(long long)((int)r3a & 0x1FFFF) * DFEAT + feat];
                float x3b = x[(long long)((int)r3b & 0x1FFFF) * DFEAT + feat];
                a0 = fmaf(__int_as_float((int)(r0a >> 32)), x0a, a0);
                a0 = fmaf(__int_as_float((int)(r0b >> 32)), x0b, a0);
                a1 = fmaf(__int_as_float((int)(r1a >> 32)), x1a, a1);
                a1 = fmaf(__int_as_float((int)(r1b >> 32)), x1b, a1);
                a2 = fmaf(__int_as_float((int)(r2a >> 32)), x2a, a2);
                a2 = fmaf(__int_as_float((int)(r2b >> 32)), x2b, a2);
                a3 = fmaf(__int_as_float((int)(r3a >> 32)), x3a, a3);
                a3 = fmaf(__int_as_float((int)(r3b >> 32)), x3b, a3);
                i0 += 4; i1 += 4; i2 += 4; i3 += 4;
            }
            // single-step quad loop
            while (i0 < e0 && i1 < e1 && i2 < e2 && i3 < e3) {
                u64 r0 = srec[i0], r1 = srec[i1], r2 = srec[i2], r3 = srec[i3];
                float x0 = x[(long long)((int)r0 & 0x1FFFF) * DFEAT + feat];
                float x1 = x[(long long)((int)r1 & 0x1FFFF) * DFEAT + feat];
                float x2 = x[(long long)((int)r2 & 0x1FFFF) * DFEAT + feat];
                float x3 = x[(long long)((int)r3 & 0x1FFFF) * DFEAT + feat];
                a0 = fmaf(__int_as_float((int)(r0 >> 32)), x0, a0);
                a1 = fmaf(__int_as_float((int)(r1 >> 32)), x1, a1);
                a2 = fmaf(__int_as_float((int)(r2 >> 32)), x2, a2);
                a3 = fmaf(__int_as_float((int)(r3 >> 32)), x3, a3);
                i0 += 2; i1 += 2; i2 += 2; i3 += 2;
            }
            while (i0 < e0) {
                u64 rr = srec[i0];
                a0 = fmaf(__int_as_float((int)(rr >> 32)),
                          x[(long long)((int)rr & 0x1FFFF) * DFEAT + feat], a0);
                i0 += 2;
            }
            while (i1 < e1) {
                u64 rr = srec[i1];
                a1 = fmaf(__int_as_float((int)(rr >> 32)),
                          x[(long long)((int)rr & 0x1FFFF) * DFEAT + feat], a1);
                i1 += 2;
            }
            while (i2 < e2) {
                u64 rr = srec[i2];
                a2 = fmaf(__int_as_float((int)(rr >> 32)),
                          x[(long long)((int)rr & 0x1FFFF) * DFEAT + feat], a2);
                i2 += 2;
            }
            while (i3 < e3) {
                u64 rr = srec[i3];
                a3 = fmaf(__int_as_float((int)(rr >> 32)),
                          x[(long long)((int)rr & 0x1FFFF) * DFEAT + feat], a3);
                i3 += 2;
            }
            accA[p] = a0; accB[p] = a1; accC[p] = a2; accD[p] = a3;
        }
        __syncthreads();    // protect srec/lcnt before next chunk
    }

    // combine halves; half 0 writes keys 4p+0/1, half 1 writes 4p+2/3
    int key0 = b * KEYS_PER_BIN + wid * 32;
    #pragma unroll
    for (int p = 0; p < 8; ++p) {
        float t0 = accA[p] + __shfl_xor(accA[p], 32, 64);
        float t1 = accB[p] + __shfl_xor(accB[p], 32, 64);
        float t2 = accC[p] + __shfl_xor(accC[p], 32, 64);
        float t3 = accD[p] + __shfl_xor(accD[p], 32, 64);
        float vA = half ? t2 : t0;
        float vB = half ? t3 : t1;
        int gkA = key0 + 4 * p + (half ? 2 : 0);
        int gkB = gkA + 1;
        if (gkA < NK) {
            int node = gkA >> 1;
            ((gkA & 1) ? mo : mi)[(long long)node * DFEAT + feat] = vA;
        }
        if (gkB < NK) {
            int node = gkB >> 1;
            ((gkB & 1) ? mo : mi)[(long long)node * DFEAT + feat] = vB;
        }
    }
}

// ---- fallback: direct atomic scatter (ws too small / N too big) ----
__global__ __launch_bounds__(256) void edge_scatter_kernel(
    const float* __restrict__ x, const int* __restrict__ ei,
    const float* __restrict__ ea,
    float* __restrict__ mi, float* __restrict__ mo, int E)
{
    long long tid = (long long)blockIdx.x * blockDim.x + threadIdx.x;
    long long total = (long long)E * 8;
    if (tid >= total) return;
    int e = (int)(tid >> 3);
    int q = (int)(tid & 7);
    int r = ei[e];
    int c = ei[E + e];
    float a = ea[e];
    const float4* x4 = (const float4*)x;
    float4 xr = x4[(long long)r * 8 + q];
    float4 xc = x4[(long long)c * 8 + q];
    float* mip = mi + (long long)c * DFEAT + q * 4;
    float* mop = mo + (long long)r * DFEAT + q * 4;
    atomicAdd(mip + 0, a * xr.x); atomicAdd(mip + 1, a * xr.y);
    atomicAdd(mip + 2, a * xr.z); atomicAdd(mip + 3, a * xr.w);
    atomicAdd(mop + 0, a * xc.x); atomicAdd(mop + 1, a * xc.y);
    atomicAdd(mop + 2, a * xc.z); atomicAdd(mop + 3, a * xc.w);
}

// ---- F. MLP: weights in VGPRs, operands broadcast via v_readlane ----
__global__ __launch_bounds__(256) void mlp_reg_kernel(
    const float* __restrict__ mi, const float* __restrict__ mo,
    const float* __restrict__ x,
    const float* __restrict__ W1, const float* __restrict__ b1,
    const float* __restrict__ W2, const float* __restrict__ b2,
    float* __restrict__ out, int N)
{
    int o   = threadIdx.x & 63;     // lane = output index
    int wid = threadIdx.x >> 6;     // wave within block

    float w1r[96], w2r[64];
    #pragma unroll
    for (int k = 0; k < 96; ++k) w1r[k] = W1[k * 64 + o];
    #pragma unroll
    for (int k = 0; k < 64; ++k) w2r[k] = W2[k * 64 + o];
    float bias1 = b1[o];
    float bias2 = b2[o];

    int stride = gridDim.x * 4;
    for (int node = blockIdx.x * 4 + wid; node < N; node += stride) {
        long long nb = (long long)node * DFEAT;
        float m01 = (o < 32) ? mi[nb + o] : mo[nb + (o - 32)];
        float m2v = (o < 32) ? x[nb + o] : 0.0f;

        float a0 = bias1, a1 = 0.0f, a2 = 0.0f, a3 = 0.0f;
        #pragma unroll
        for (int k = 0; k < 64; k += 4) {
            a0 = fmaf(rdlane(m01, k + 0), w1r[k + 0], a0);
            a1 = fmaf(rdlane(m01, k + 1), w1r[k + 1], a1);
            a2 = fmaf(rdlane(m01, k + 2), w1r[k + 2], a2);
            a3 = fmaf(rdlane(m01, k + 3), w1r[k + 3], a3);
        }
        #pragma unroll
        for (int k = 0; k < 32; k += 4) {
            a0 = fmaf(rdlane(m2v, k + 0), w1r[64 + k + 0], a0);
            a1 = fmaf(rdlane(m2v, k + 1), w1r[64 + k + 1], a1);
            a2 = fmaf(rdlane(m2v, k + 2), w1r[64 + k + 2], a2);
            a3 = fmaf(rdlane(m2v, k + 3), w1r[64 + k + 3], a3);
        }
        float h = tanhf(((a0 + a1) + (a2 + a3)));

        float c0 = bias2, c1 = 0.0f, c2 = 0.0f, c3 = 0.0f;
        #pragma unroll
        for (int k = 0; k < 64; k += 4) {
            c0 = fmaf(rdlane(h, k + 0), w2r[k + 0], c0);
            c1 = fmaf(rdlane(h, k + 1), w2r[k + 1], c1);
            c2 = fmaf(rdlane(h, k + 2), w2r[k + 2], c2);
            c3 = fmaf(rdlane(h, k + 3), w2r[k + 3], c3);
        }
        out[(long long)node * OFEAT + o] = tanhf(((c0 + c1) + (c2 + c3)));
    }
}

extern "C" void kernel_launch(void* const* d_in, const int* in_sizes, int n_in,
                              void* d_out, int out_size, void* d_ws, size_t ws_size,
                              hipStream_t stream) {
    const float* x  = (const float*)d_in[0];
    const int*   ei = (const int*)  d_in[1];
    const float* ea = (const float*)d_in[2];
    const float* W1 = (const float*)d_in[3];
    const float* b1 = (const float*)d_in[4];
    const float* W2 = (const float*)d_in[5];
    const float* b2 = (const float*)d_in[6];
    float* out = (float*)d_out;

    int N    = in_sizes[0] / DFEAT;              // 100000
    int E    = in_sizes[2];                      // 1600000
    int NK   = 2 * N;
    int NBIN = (NK + KEYS_PER_BIN - 1) / KEYS_PER_BIN;   // 1563
    int nPB  = (E + EPB - 1) / EPB;                      // 782

    float* mi = (float*)d_ws;
    float* mo = mi + (size_t)N * DFEAT;

    size_t paySlots = (size_t)2 * E + NBIN;      // + even-padding slack
    size_t need = (size_t)N * DFEAT * 2 * 4      // mi, mo
                + paySlots * 8                   // records
                + (size_t)nPB * NBIN * 4 * 2     // blockhist + ofsT
                + (size_t)NBIN * 4 * 2 + 64;     // bintotal + binbase

    if (ws_size >= need && N <= (1 << 17) && NBIN <= MAXBIN) {
        u64* pay       = (u64*)(mo + (size_t)N * DFEAT);
        int* blockhist = (int*)(pay + paySlots);
        int* ofsT      = blockhist + (size_t)nPB * NBIN;
        int* bintotal  = ofsT + (size_t)nPB * NBIN;
        int* binbase   = bintotal + NBIN;

        hist_part<<<nPB, 256, 0, stream>>>(ei, blockhist, E, NBIN);
        colscan<<<NBIN, 64, 0, stream>>>(blockhist, ofsT, bintotal, nPB, NBIN);
        scan_bins<<<1, 1024, 0, stream>>>(bintotal, binbase, NBIN);
        partition_kernel<<<nPB, 256, 0, stream>>>(ei, ea, ofsT, binbase,
                                                  pay, E, NBIN, nPB);
        accum_sortgather<<<NBIN, 256, 0, stream>>>(x, binbase, bintotal, pay,
                                                   mi, mo, NK);
    } else {
        hipMemsetAsync(d_ws, 0, (size_t)N * DFEAT * 2 * sizeof(float), stream);
        long long total = (long long)E * 8;
        int nblocks = (int)((total + 255) / 256);
        edge_scatter_kernel<<<nblocks, 256, 0, stream>>>(x, ei, ea, mi, mo, E);
    }

    mlp_reg_kernel<<<512, 256, 0, stream>>>(mi, mo, x, W1, b1, W2, b2, out, N);
}

// Round 13
// 236.124 us; speedup vs baseline: 1.1899x; 1.1899x over previous
//
#include <hip/hip_runtime.h>
#include <hip/hip_bf16.h>

// NodeNetwork: mi = segsum(ea*x[row] -> col), mo = segsum(ea*x[col] -> row)
// out = tanh(tanh([mi|mo|x] @ W1 + b1) @ W2 + b2)
// N=100000, D=32, O=64, E=1600000
//
// R13: revert R12's reg-stash + x2 unroll (VGPR 68 -> occupancy 24%, FETCH
// unchanged -> pay re-read was already L2-hit; this kernel's currency is
// WAVES, not ILP). accum now 512-thread blocks / 8 waves, wave owns 16 keys:
// LDS 26KB -> 4 blocks/CU x 8 waves = 32 waves/CU (cap) vs R11's 75%.
// Gather body identical to R11 (quad chains, 44 VGPR).
// R11 baseline: 257us total, accum 117us @ 34% occupancy.

#define DFEAT 32
#define OFEAT 64
#define EPB   2048            // edges per partition block -> 4096 records
#define KEYS_PER_BIN 128      // partition bin = key >> 7 ; lkey = key & 127
#define MAXBIN 2048
#define CAP   3072            // records staged per chunk (24 KB)

typedef unsigned long long u64;

__device__ __forceinline__ float rdlane(float v, int l) {
    return __int_as_float(__builtin_amdgcn_readlane(__float_as_int(v), l));
}

// ---- A. per-block histogram over bins ----
__global__ __launch_bounds__(256) void hist_part(
    const int* __restrict__ ei, int* __restrict__ blockhist, int E, int NBIN)
{
    __shared__ int lh[MAXBIN];
    int blk = blockIdx.x;
    for (int i = threadIdx.x; i < NBIN; i += 256) lh[i] = 0;
    __syncthreads();
    int e0 = blk * EPB;
    #pragma unroll
    for (int j = 0; j < 8; ++j) {
        int e = e0 + j * 256 + threadIdx.x;
        if (e < E) {
            int r = ei[e], c = ei[E + e];
            atomicAdd(&lh[(2 * c) >> 7], 1);
            atomicAdd(&lh[(2 * r + 1) >> 7], 1);
        }
    }
    __syncthreads();
    for (int i = threadIdx.x; i < NBIN; i += 256)
        blockhist[(long long)blk * NBIN + i] = lh[i];
}

// ---- B. column scan: per-bin prefix over blocks -> ofsT, bintotal ----
__global__ __launch_bounds__(64) void colscan(
    const int* __restrict__ blockhist, int* __restrict__ ofsT,
    int* __restrict__ bintotal, int nPB, int NBIN)
{
    int bin  = blockIdx.x;
    int lane = threadIdx.x;
    int run = 0;
    for (int b0 = 0; b0 < nPB; b0 += 64) {
        int b = b0 + lane;
        int v = (b < nPB) ? blockhist[(long long)b * NBIN + bin] : 0;
        int s = v;
        #pragma unroll
        for (int d = 1; d < 64; d <<= 1) {
            int t = __shfl_up(s, d, 64);
            if (lane >= d) s += t;
        }
        if (b < nPB) ofsT[(long long)bin * nPB + b] = s - v + run;
        run += __shfl(s, 63, 64);
    }
    if (lane == 0) bintotal[bin] = run;
}

// ---- C. exclusive scan of (even-padded) bin totals, up to 2048 bins ----
__global__ __launch_bounds__(1024) void scan_bins(
    const int* __restrict__ bintotal, int* __restrict__ binbase, int NBIN)
{
    __shared__ int s[1024];
    int t = threadIdx.x;
    int i0 = 2 * t, i1 = 2 * t + 1;
    int p0 = (i0 < NBIN) ? ((bintotal[i0] + 1) & ~1) : 0;  // even-pad -> 16B align
    int p1 = (i1 < NBIN) ? ((bintotal[i1] + 1) & ~1) : 0;
    int v = p0 + p1;
    s[t] = v;
    __syncthreads();
    for (int o = 1; o < 1024; o <<= 1) {
        int u = (t >= o) ? s[t - o] : 0;
        __syncthreads();
        s[t] += u;
        __syncthreads();
    }
    int excl = s[t] - v;
    if (i0 < NBIN) binbase[i0] = excl;
    if (i1 < NBIN) binbase[i1] = excl + p0;
}

// ---- D. partition: LDS reorder + coalesced flush (binof tag) ----
__global__ __launch_bounds__(256) void partition_kernel(
    const int* __restrict__ ei, const float* __restrict__ ea,
    const int* __restrict__ ofsT, const int* __restrict__ binbase,
    u64* __restrict__ pay, int E, int NBIN, int nPB)
{
    __shared__ int lofs[MAXBIN + 1];
    __shared__ int lcur[MAXBIN];
    __shared__ int lbase[MAXBIN];
    __shared__ u64 stag[2 * EPB];             // 32 KB
    __shared__ unsigned short binof[2 * EPB]; // 8 KB
    int blk = blockIdx.x, tid = threadIdx.x;
    int e0 = blk * EPB;

    for (int i = tid; i < NBIN; i += 256) lcur[i] = 0;
    __syncthreads();

    // pass 1: load edges (kept in regs), LDS histogram
    int r[8], c[8]; float a[8]; bool valid[8];
    #pragma unroll
    for (int j = 0; j < 8; ++j) {
        int e = e0 + j * 256 + tid;
        valid[j] = (e < E);
        if (valid[j]) {
            r[j] = ei[e]; c[j] = ei[E + e]; a[j] = ea[e];
            atomicAdd(&lcur[(2 * c[j]) >> 7], 1);
            atomicAdd(&lcur[(2 * r[j] + 1) >> 7], 1);
        }
    }
    __syncthreads();

    // wave 0: exclusive scan lcur -> lofs
    if (tid < 64) {
        int runc = 0;
        for (int b0 = 0; b0 < NBIN; b0 += 64) {
            int i = b0 + tid;
            int v = (i < NBIN) ? lcur[i] : 0;
            int s = v;
            #pragma unroll
            for (int d = 1; d < 64; d <<= 1) {
                int t2 = __shfl_up(s, d, 64);
                if (tid >= d) s += t2;
            }
            if (i < NBIN) lofs[i] = s - v + runc;
            runc += __shfl(s, 63, 64);
        }
        if (tid == 0) lofs[NBIN] = runc;
    }
    __syncthreads();

    // reset tickets, compute global bases for this block
    for (int i = tid; i < NBIN; i += 256) {
        lcur[i] = 0;
        lbase[i] = binbase[i] + ofsT[(long long)i * nPB + blk];
    }
    __syncthreads();

    // pass 2: place records into LDS staging (sorted by bin) + bin tag
    #pragma unroll
    for (int j = 0; j < 8; ++j) {
        if (valid[j]) {
            unsigned int ab = (unsigned int)__float_as_int(a[j]);
            {
                int key = 2 * c[j]; int bin = key >> 7;      // mi: src = r
                int t2 = atomicAdd(&lcur[bin], 1);
                int pos = lofs[bin] + t2;
                stag[pos] = ((u64)ab << 32) |
                    (unsigned int)(r[j] | ((key & 127) << 17));
                binof[pos] = (unsigned short)bin;
            }
            {
                int key = 2 * r[j] + 1; int bin = key >> 7;  // mo: src = c
                int t2 = atomicAdd(&lcur[bin], 1);
                int pos = lofs[bin] + t2;
                stag[pos] = ((u64)ab << 32) |
                    (unsigned int)(c[j] | ((key & 127) << 17));
                binof[pos] = (unsigned short)bin;
            }
        }
    }
    __syncthreads();

    // flush: contiguous runs per bin -> mostly full-line global writes
    int total = lofs[NBIN];
    for (int i = tid; i < total; i += 256) {
        int bn = binof[i];
        pay[lbase[bn] + (i - lofs[bn])] = stag[i];
    }
}

// ---- E. accum: 512 threads / 8 waves; wave owns 16 keys; quad chains ----
__global__ __launch_bounds__(512) void accum_sortgather(
    const float* __restrict__ x,
    const int* __restrict__ binbase, const int* __restrict__ bintotal,
    const u64* __restrict__ pay,
    float* __restrict__ mi, float* __restrict__ mo, int NK)
{
    __shared__ u64 srec[CAP];                 // 24 KB, records sorted by key
    __shared__ int lcnt[KEYS_PER_BIN];
    __shared__ int lofs[KEYS_PER_BIN];
    __shared__ int lcur[KEYS_PER_BIN];

    int b = blockIdx.x, tid = threadIdx.x;
    int base = binbase[b];
    int n    = bintotal[b];
    int wid  = tid >> 6;        // 0..7: wave -> owns keys [wid*16, wid*16+16)
    int lane = tid & 63;
    int half = lane >> 5;       // records strided by 2 across halves
    int feat = lane & 31;

    float accA[4], accB[4], accC[4], accD[4];
    #pragma unroll
    for (int p = 0; p < 4; ++p) {
        accA[p] = 0.0f; accB[p] = 0.0f; accC[p] = 0.0f; accD[p] = 0.0f;
    }

    for (int c0 = 0; c0 < n; c0 += CAP) {
        int cn = min(n - c0, CAP);
        if (tid < KEYS_PER_BIN) lcnt[tid] = 0;
        __syncthreads();
        // count keys in this chunk
        for (int i = tid; i < cn; i += 512)
            atomicAdd(&lcnt[((int)pay[base + c0 + i] >> 17) & 127], 1);
        __syncthreads();
        // exclusive scan of 128 counters (wave 0, 2 keys/lane)
        if (tid < 64) {
            int v0 = lcnt[2 * tid], v1 = lcnt[2 * tid + 1];
            int s = v0 + v1, ss = s;
            #pragma unroll
            for (int d = 1; d < 64; d <<= 1) {
                int t = __shfl_up(ss, d, 64);
                if (tid >= d) ss += t;
            }
            int excl = ss - s;
            lofs[2 * tid] = excl;      lofs[2 * tid + 1] = excl + v0;
            lcur[2 * tid] = excl;      lcur[2 * tid + 1] = excl + v0;
        }
        __syncthreads();
        // place records sorted by key
        for (int i = tid; i < cn; i += 512) {
            u64 v = pay[base + c0 + i];              // L2-hot re-read
            int t2 = atomicAdd(&lcur[((int)v >> 17) & 127], 1);
            srec[t2] = v;
        }
        __syncthreads();

        // gather: 4 quads of keys per wave; 4 independent chains per half
        #pragma unroll
        for (int p = 0; p < 4; ++p) {
            int kb = wid * 16 + 4 * p;
            int s0 = lofs[kb + 0], e0 = s0 + lcnt[kb + 0];
            int s1 = lofs[kb + 1], e1 = s1 + lcnt[kb + 1];
            int s2 = lofs[kb + 2], e2 = s2 + lcnt[kb + 2];
            int s3 = lofs[kb + 3], e3 = s3 + lcnt[kb + 3];
            int i0 = s0 + half, i1 = s1 + half, i2 = s2 + half, i3 = s3 + half;
            float a0 = accA[p], a1 = accB[p], a2 = accC[p], a3 = accD[p];
            while (i0 < e0 && i1 < e1 && i2 < e2 && i3 < e3) {
                u64 r0 = srec[i0], r1 = srec[i1], r2 = srec[i2], r3 = srec[i3];
                float x0 = x[(long long)((int)r0 & 0x1FFFF) * DFEAT + feat];
                float x1 = x[(long long)((int)r1 & 0x1FFFF) * DFEAT + feat];
                float x2 = x[(long long)((int)r2 & 0x1FFFF) * DFEAT + feat];
                float x3 = x[(long long)((int)r3 & 0x1FFFF) * DFEAT + feat];
                a0 = fmaf(__int_as_float((int)(r0 >> 32)), x0, a0);
                a1 = fmaf(__int_as_float((int)(r1 >> 32)), x1, a1);
                a2 = fmaf(__int_as_float((int)(r2 >> 32)), x2, a2);
                a3 = fmaf(__int_as_float((int)(r3 >> 32)), x3, a3);
                i0 += 2; i1 += 2; i2 += 2; i3 += 2;
            }
            while (i0 < e0) {
                u64 rr = srec[i0];
                a0 = fmaf(__int_as_float((int)(rr >> 32)),
                          x[(long long)((int)rr & 0x1FFFF) * DFEAT + feat], a0);
                i0 += 2;
            }
            while (i1 < e1) {
                u64 rr = srec[i1];
                a1 = fmaf(__int_as_float((int)(rr >> 32)),
                          x[(long long)((int)rr & 0x1FFFF) * DFEAT + feat], a1);
                i1 += 2;
            }
            while (i2 < e2) {
                u64 rr = srec[i2];
                a2 = fmaf(__int_as_float((int)(rr >> 32)),
                          x[(long long)((int)rr & 0x1FFFF) * DFEAT + feat], a2);
                i2 += 2;
            }
            while (i3 < e3) {
                u64 rr = srec[i3];
                a3 = fmaf(__int_as_float((int)(rr >> 32)),
                          x[(long long)((int)rr & 0x1FFFF) * DFEAT + feat], a3);
                i3 += 2;
            }
            accA[p] = a0; accB[p] = a1; accC[p] = a2; accD[p] = a3;
        }
        __syncthreads();    // protect srec/lcnt before next chunk
    }

    // combine halves; half 0 writes keys 4p+0/1, half 1 writes 4p+2/3
    int key0 = b * KEYS_PER_BIN + wid * 16;
    #pragma unroll
    for (int p = 0; p < 4; ++p) {
        float t0 = accA[p] + __shfl_xor(accA[p], 32, 64);
        float t1 = accB[p] + __shfl_xor(accB[p], 32, 64);
        float t2 = accC[p] + __shfl_xor(accC[p], 32, 64);
        float t3 = accD[p] + __shfl_xor(accD[p], 32, 64);
        float vA = half ? t2 : t0;
        float vB = half ? t3 : t1;
        int gkA = key0 + 4 * p + (half ? 2 : 0);
        int gkB = gkA + 1;
        if (gkA < NK) {
            int node = gkA >> 1;
            ((gkA & 1) ? mo : mi)[(long long)node * DFEAT + feat] = vA;
        }
        if (gkB < NK) {
            int node = gkB >> 1;
            ((gkB & 1) ? mo : mi)[(long long)node * DFEAT + feat] = vB;
        }
    }
}

// ---- fallback: direct atomic scatter (ws too small / N too big) ----
__global__ __launch_bounds__(256) void edge_scatter_kernel(
    const float* __restrict__ x, const int* __restrict__ ei,
    const float* __restrict__ ea,
    float* __restrict__ mi, float* __restrict__ mo, int E)
{
    long long tid = (long long)blockIdx.x * blockDim.x + threadIdx.x;
    long long total = (long long)E * 8;
    if (tid >= total) return;
    int e = (int)(tid >> 3);
    int q = (int)(tid & 7);
    int r = ei[e];
    int c = ei[E + e];
    float a = ea[e];
    const float4* x4 = (const float4*)x;
    float4 xr = x4[(long long)r * 8 + q];
    float4 xc = x4[(long long)c * 8 + q];
    float* mip = mi + (long long)c * DFEAT + q * 4;
    float* mop = mo + (long long)r * DFEAT + q * 4;
    atomicAdd(mip + 0, a * xr.x); atomicAdd(mip + 1, a * xr.y);
    atomicAdd(mip + 2, a * xr.z); atomicAdd(mip + 3, a * xr.w);
    atomicAdd(mop + 0, a * xc.x); atomicAdd(mop + 1, a * xc.y);
    atomicAdd(mop + 2, a * xc.z); atomicAdd(mop + 3, a * xc.w);
}

// ---- F. MLP: weights in VGPRs, operands broadcast via v_readlane ----
__global__ __launch_bounds__(256) void mlp_reg_kernel(
    const float* __restrict__ mi, const float* __restrict__ mo,
    const float* __restrict__ x,
    const float* __restrict__ W1, const float* __restrict__ b1,
    const float* __restrict__ W2, const float* __restrict__ b2,
    float* __restrict__ out, int N)
{
    int o   = threadIdx.x & 63;     // lane = output index
    int wid = threadIdx.x >> 6;     // wave within block

    float w1r[96], w2r[64];
    #pragma unroll
    for (int k = 0; k < 96; ++k) w1r[k] = W1[k * 64 + o];
    #pragma unroll
    for (int k = 0; k < 64; ++k) w2r[k] = W2[k * 64 + o];
    float bias1 = b1[o];
    float bias2 = b2[o];

    int stride = gridDim.x * 4;
    for (int node = blockIdx.x * 4 + wid; node < N; node += stride) {
        long long nb = (long long)node * DFEAT;
        float m01 = (o < 32) ? mi[nb + o] : mo[nb + (o - 32)];
        float m2v = (o < 32) ? x[nb + o] : 0.0f;

        float a0 = bias1, a1 = 0.0f, a2 = 0.0f, a3 = 0.0f;
        #pragma unroll
        for (int k = 0; k < 64; k += 4) {
            a0 = fmaf(rdlane(m01, k + 0), w1r[k + 0], a0);
            a1 = fmaf(rdlane(m01, k + 1), w1r[k + 1], a1);
            a2 = fmaf(rdlane(m01, k + 2), w1r[k + 2], a2);
            a3 = fmaf(rdlane(m01, k + 3), w1r[k + 3], a3);
        }
        #pragma unroll
        for (int k = 0; k < 32; k += 4) {
            a0 = fmaf(rdlane(m2v, k + 0), w1r[64 + k + 0], a0);
            a1 = fmaf(rdlane(m2v, k + 1), w1r[64 + k + 1], a1);
            a2 = fmaf(rdlane(m2v, k + 2), w1r[64 + k + 2], a2);
            a3 = fmaf(rdlane(m2v, k + 3), w1r[64 + k + 3], a3);
        }
        float h = tanhf(((a0 + a1) + (a2 + a3)));

        float c0 = bias2, c1 = 0.0f, c2 = 0.0f, c3 = 0.0f;
        #pragma unroll
        for (int k = 0; k < 64; k += 4) {
            c0 = fmaf(rdlane(h, k + 0), w2r[k + 0], c0);
            c1 = fmaf(rdlane(h, k + 1), w2r[k + 1], c1);
            c2 = fmaf(rdlane(h, k + 2), w2r[k + 2], c2);
            c3 = fmaf(rdlane(h, k + 3), w2r[k + 3], c3);
        }
        out[(long long)node * OFEAT + o] = tanhf(((c0 + c1) + (c2 + c3)));
    }
}

extern "C" void kernel_launch(void* const* d_in, const int* in_sizes, int n_in,
                              void* d_out, int out_size, void* d_ws, size_t ws_size,
                              hipStream_t stream) {
    const float* x  = (const float*)d_in[0];
    const int*   ei = (const int*)  d_in[1];
    const float* ea = (const float*)d_in[2];
    const float* W1 = (const float*)d_in[3];
    const float* b1 = (const float*)d_in[4];
    const float* W2 = (const float*)d_in[5];
    const float* b2 = (const float*)d_in[6];
    float* out = (float*)d_out;

    int N    = in_sizes[0] / DFEAT;              // 100000
    int E    = in_sizes[2];                      // 1600000
    int NK   = 2 * N;
    int NBIN = (NK + KEYS_PER_BIN - 1) / KEYS_PER_BIN;   // 1563
    int nPB  = (E + EPB - 1) / EPB;                      // 782

    float* mi = (float*)d_ws;
    float* mo = mi + (size_t)N * DFEAT;

    size_t paySlots = (size_t)2 * E + NBIN;      // + even-padding slack
    size_t need = (size_t)N * DFEAT * 2 * 4      // mi, mo
                + paySlots * 8                   // records
                + (size_t)nPB * NBIN * 4 * 2     // blockhist + ofsT
                + (size_t)NBIN * 4 * 2 + 64;     // bintotal + binbase

    if (ws_size >= need && N <= (1 << 17) && NBIN <= MAXBIN) {
        u64* pay       = (u64*)(mo + (size_t)N * DFEAT);
        int* blockhist = (int*)(pay + paySlots);
        int* ofsT      = blockhist + (size_t)nPB * NBIN;
        int* bintotal  = ofsT + (size_t)nPB * NBIN;
        int* binbase   = bintotal + NBIN;

        hist_part<<<nPB, 256, 0, stream>>>(ei, blockhist, E, NBIN);
        colscan<<<NBIN, 64, 0, stream>>>(blockhist, ofsT, bintotal, nPB, NBIN);
        scan_bins<<<1, 1024, 0, stream>>>(bintotal, binbase, NBIN);
        partition_kernel<<<nPB, 256, 0, stream>>>(ei, ea, ofsT, binbase,
                                                  pay, E, NBIN, nPB);
        accum_sortgather<<<NBIN, 512, 0, stream>>>(x, binbase, bintotal, pay,
                                                   mi, mo, NK);
    } else {
        hipMemsetAsync(d_ws, 0, (size_t)N * DFEAT * 2 * sizeof(float), stream);
        long long total = (long long)E * 8;
        int nblocks = (int)((total + 255) / 256);
        edge_scatter_kernel<<<nblocks, 256, 0, stream>>>(x, ei, ea, mi, mo, E);
    }

    mlp_reg_kernel<<<512, 256, 0, stream>>>(mi, mo, x, W1, b1, W2, b2, out, N);
}